// Round 1
// baseline (39.202 us; speedup 1.0000x reference)
//
#include <hip/hip_runtime.h>

#define NSAMP 4096

// Per-(sample,level) partial loss:
//   loss_i = (A/T^2 - 2B/T + C) / (S*S)
// with T=sum(c), A=sum(c^2), B=sum(c*h), C=sum(h^2), h = gy[y]*gx[x]
template <int S, int STRIDE>
__global__ __launch_bounds__(256) void heat_partial_kernel(
    const float* __restrict__ cls,      // (NSAMP, S*S) contiguous
    const float* __restrict__ gt,       // (NSAMP, 4)
    float* __restrict__ partial)        // (NSAMP,)
{
    constexpr int SS = S * S;
    const int sid = blockIdx.x;
    const float* __restrict__ c_base = cls + (size_t)sid * SS;

    // Gaussian parameters from gt_bbox (uniform across block; cheap per-thread)
    const float b0 = gt[sid * 4 + 0] - 64.0f;
    const float b1 = gt[sid * 4 + 1] - 64.0f;
    const float b2 = gt[sid * 4 + 2] - 64.0f;
    const float b3 = gt[sid * 4 + 3] - 64.0f;
    const float inv_stride = 1.0f / (float)STRIDE;
    const float mu_x  = 0.5f * (b0 + b2) * inv_stride;
    const float mu_y  = 0.5f * (b1 + b3) * inv_stride;
    const float sig_x = 0.2f * (b2 - b0) * inv_stride;
    const float sig_y = 0.2f * (b3 - b1) * inv_stride;
    const float isx = 1.0f / sig_x;
    const float isy = 1.0f / sig_y;
    const float INV_SQRT_2PI = 0.39894228040143267794f;
    const float ax = INV_SQRT_2PI * isx;
    const float ay = INV_SQRT_2PI * isy;

    __shared__ float gx[64];
    __shared__ float gy[64];
    __shared__ float redbuf[4][4];

    const int tid = threadIdx.x;
    // One __expf per grid coordinate instead of per element (separable heatmap).
    if (tid < 64) {
        float d = ((float)tid - mu_x) * isx;
        gx[tid] = (tid < S) ? ax * __expf(-0.5f * d * d) : 0.0f;
    } else if (tid < 128) {
        int yy = tid - 64;
        float d = ((float)yy - mu_y) * isy;
        gy[yy] = (yy < S) ? ay * __expf(-0.5f * d * d) : 0.0f;
    }
    __syncthreads();

    float T = 0.0f, A = 0.0f, B = 0.0f, C = 0.0f;
    for (int idx = tid; idx < SS; idx += 256) {
        int y = idx / S;            // S is constexpr -> magic-mul
        int x = idx - y * S;
        float c = c_base[idx];
        float h = gy[y] * gx[x];
        T += c;
        A = fmaf(c, c, A);
        B = fmaf(c, h, B);
        C = fmaf(h, h, C);
    }

    // wave64 shuffle reduction
    #pragma unroll
    for (int off = 32; off > 0; off >>= 1) {
        T += __shfl_down(T, off);
        A += __shfl_down(A, off);
        B += __shfl_down(B, off);
        C += __shfl_down(C, off);
    }
    const int lane = tid & 63;
    const int wid  = tid >> 6;
    if (lane == 0) {
        redbuf[wid][0] = T; redbuf[wid][1] = A;
        redbuf[wid][2] = B; redbuf[wid][3] = C;
    }
    __syncthreads();
    if (tid == 0) {
        float t = 0.0f, a = 0.0f, b = 0.0f, cc = 0.0f;
        #pragma unroll
        for (int w = 0; w < 4; ++w) {
            t  += redbuf[w][0];
            a  += redbuf[w][1];
            b  += redbuf[w][2];
            cc += redbuf[w][3];
        }
        const float invT = 1.0f / t;
        const float loss = (fmaf(a * invT, invT, -2.0f * b * invT) + cc) / (float)SS;
        partial[sid] = loss;
    }
}

// Deterministic fixed-order final reduction of 2*NSAMP partials.
__global__ __launch_bounds__(256) void heat_final_kernel(
    const float* __restrict__ partial, float* __restrict__ out)
{
    __shared__ float red[4];
    const int tid = threadIdx.x;
    float s = 0.0f;
    for (int i = tid; i < 2 * NSAMP; i += 256) s += partial[i];
    #pragma unroll
    for (int off = 32; off > 0; off >>= 1) s += __shfl_down(s, off);
    if ((tid & 63) == 0) red[tid >> 6] = s;
    __syncthreads();
    if (tid == 0) out[0] = red[0] + red[1] + red[2] + red[3];
}

extern "C" void kernel_launch(void* const* d_in, const int* in_sizes, int n_in,
                              void* d_out, int out_size, void* d_ws, size_t ws_size,
                              hipStream_t stream) {
    // inputs: 0=cls0 (N,1,63,63), 1=reg0 (unused), 2=cls1 (N,1,31,31),
    //         3=reg1 (unused), 4=gt_bbox (N,4)
    const float* cls0 = (const float*)d_in[0];
    const float* cls1 = (const float*)d_in[2];
    const float* gt   = (const float*)d_in[4];
    float* out = (float*)d_out;
    float* ws  = (float*)d_ws;   // needs 2*NSAMP floats = 32 KiB

    heat_partial_kernel<63, 4><<<NSAMP, 256, 0, stream>>>(cls0, gt, ws);
    heat_partial_kernel<31, 8><<<NSAMP, 256, 0, stream>>>(cls1, gt, ws + NSAMP);
    heat_final_kernel<<<1, 256, 0, stream>>>(ws, out);
}

// Round 2
// 26.702 us; speedup vs baseline: 1.4681x; 1.4681x over previous
//
#include <hip/hip_runtime.h>

#define NSAMP 4096

// loss_i = (A/T^2 - 2B/T + C) / (S*S)
// T = sum(c), A = sum(c^2), B = sum(c*h), C = sum(h^2), h[y][x] = gy[y]*gx[x]
// B = sum_x gx[x] * (sum_y c[y][x]*gy[y])   (column factorization)
// C = (sum_y gy^2) * (sum_x gx^2)           (fully separable, no per-element work)
template <int S, int STRIDE, int XLANES>
__device__ __forceinline__ void level_loss(
    const float* __restrict__ cls,   // (NSAMP, S*S)
    const float* __restrict__ gt,    // (NSAMP, 4)
    int sid,
    float* __restrict__ partial_slot,
    float* gx, float* gy, float* red /*[12]*/, float* sg /*[2]*/)
{
    constexpr int SS = S * S;
    constexpr int NROWS = 256 / XLANES;
    const float* __restrict__ c_base = cls + (size_t)sid * SS;
    const int tid = threadIdx.x;

    const float b0 = gt[sid * 4 + 0] - 64.0f;
    const float b1 = gt[sid * 4 + 1] - 64.0f;
    const float b2 = gt[sid * 4 + 2] - 64.0f;
    const float b3 = gt[sid * 4 + 3] - 64.0f;
    constexpr float invs = 1.0f / (float)STRIDE;
    const float mu_x = 0.5f * (b0 + b2) * invs;
    const float mu_y = 0.5f * (b1 + b3) * invs;
    const float isx = 1.0f / (0.2f * (b2 - b0) * invs);
    const float isy = 1.0f / (0.2f * (b3 - b1) * invs);
    const float INV_SQRT_2PI = 0.39894228040143267794f;
    const float ax = INV_SQRT_2PI * isx;
    const float ay = INV_SQRT_2PI * isy;

    // Waves 0/1 build gx/gy tables AND reduce their squares (for C) in one pass.
    if (tid < 128) {
        const bool isX = (tid < 64);
        const int p = tid & 63;
        const float mu = isX ? mu_x : mu_y;
        const float is = isX ? isx : isy;
        const float aa = isX ? ax : ay;
        float d = ((float)p - mu) * is;
        float v = (p < S) ? aa * __expf(-0.5f * d * d) : 0.0f;
        (isX ? gx : gy)[p] = v;
        float v2 = v * v;
        #pragma unroll
        for (int off = 32; off > 0; off >>= 1) v2 += __shfl_down(v2, off);
        if (p == 0) sg[isX ? 0 : 1] = v2;
    }
    __syncthreads();

    const int x  = tid & (XLANES - 1);
    const int ty = tid / XLANES;
    const float gxv = gx[x];

    float T = 0.0f, A = 0.0f, Bc = 0.0f;
    if (x < S) {
        #pragma unroll 4
        for (int y = ty; y < S; y += NROWS) {
            float c   = c_base[y * S + x];   // coalesced: consecutive lanes -> consecutive cols
            float gyv = gy[y];               // wave-broadcast LDS read
            T += c;
            A  = fmaf(c, c, A);
            Bc = fmaf(c, gyv, Bc);
        }
    }
    float B = Bc * gxv;

    #pragma unroll
    for (int off = 32; off > 0; off >>= 1) {
        T += __shfl_down(T, off);
        A += __shfl_down(A, off);
        B += __shfl_down(B, off);
    }
    const int lane = tid & 63;
    const int wid  = tid >> 6;
    if (lane == 0) { red[wid * 3 + 0] = T; red[wid * 3 + 1] = A; red[wid * 3 + 2] = B; }
    __syncthreads();
    if (tid == 0) {
        float t = red[0] + red[3] + red[6] + red[9];
        float a = red[1] + red[4] + red[7] + red[10];
        float b = red[2] + red[5] + red[8] + red[11];
        float cc = sg[0] * sg[1];
        float invT = 1.0f / t;
        *partial_slot = (fmaf(a * invT, invT, -2.0f * b * invT) + cc) * (1.0f / (float)SS);
    }
}

__global__ __launch_bounds__(256) void heat_fused_kernel(
    const float* __restrict__ cls0, const float* __restrict__ cls1,
    const float* __restrict__ gt, float* __restrict__ partial)
{
    __shared__ float gx[64], gy[64], red[12], sg[2];
    const int bid = blockIdx.x;
    if (bid < NSAMP) {
        level_loss<63, 4, 64>(cls0, gt, bid, partial + bid, gx, gy, red, sg);
    } else {
        level_loss<31, 8, 32>(cls1, gt, bid - NSAMP, partial + bid, gx, gy, red, sg);
    }
}

// Deterministic fixed-order final reduction of 2*NSAMP = 8192 partials.
__global__ __launch_bounds__(1024) void heat_final_kernel(
    const float* __restrict__ partial, float* __restrict__ out)
{
    __shared__ float red[16];
    const int tid = threadIdx.x;
    float v[8];
    #pragma unroll
    for (int i = 0; i < 8; ++i) v[i] = partial[tid + i * 1024];  // 8 independent loads
    float s = 0.0f;
    #pragma unroll
    for (int i = 0; i < 8; ++i) s += v[i];
    #pragma unroll
    for (int off = 32; off > 0; off >>= 1) s += __shfl_down(s, off);
    if ((tid & 63) == 0) red[tid >> 6] = s;
    __syncthreads();
    if (tid == 0) {
        float t = 0.0f;
        #pragma unroll
        for (int w = 0; w < 16; ++w) t += red[w];
        out[0] = t;
    }
}

extern "C" void kernel_launch(void* const* d_in, const int* in_sizes, int n_in,
                              void* d_out, int out_size, void* d_ws, size_t ws_size,
                              hipStream_t stream) {
    // inputs: 0=cls0 (N,1,63,63), 1=reg0 (unused), 2=cls1 (N,1,31,31),
    //         3=reg1 (unused), 4=gt_bbox (N,4)
    const float* cls0 = (const float*)d_in[0];
    const float* cls1 = (const float*)d_in[2];
    const float* gt   = (const float*)d_in[4];
    float* out = (float*)d_out;
    float* ws  = (float*)d_ws;   // 2*NSAMP floats = 32 KiB

    heat_fused_kernel<<<2 * NSAMP, 256, 0, stream>>>(cls0, cls1, gt, ws);
    heat_final_kernel<<<1, 1024, 0, stream>>>(ws, out);
}

// Round 3
// 26.064 us; speedup vs baseline: 1.5041x; 1.0245x over previous
//
#include <hip/hip_runtime.h>

#define NSAMP 4096

// Per-sample loss over both pyramid levels, one block per sample.
// loss = sum_levels (A/T^2 - 2B/T + C) / (S*S)
//   T = sum c, A = sum c^2, B = sum c*h, C = (sum gy^2)(sum gx^2)
//   B factorized per column: B = sum_x gx[x] * (sum_y c[y][x] * gy[y])
__global__ __launch_bounds__(256) void heat_fused_kernel(
    const float* __restrict__ cls0,   // (NSAMP, 63*63)
    const float* __restrict__ cls1,   // (NSAMP, 31*31)
    const float* __restrict__ gt,     // (NSAMP, 4)
    float* __restrict__ partial)      // (NSAMP,)
{
    __shared__ float g0x[64], g0y[64], g1x[32], g1y[32];
    __shared__ float red[4][6];
    __shared__ float sg[4];           // {sum gx0^2, sum gy0^2, sum gx1^2, sum gy1^2}

    const int sid  = blockIdx.x;
    const int tid  = threadIdx.x;
    const int lane = tid & 63;
    const int wid  = tid >> 6;

    const float4 bb = *reinterpret_cast<const float4*>(gt + (size_t)sid * 4);
    const float cx = 0.5f * (bb.x + bb.z) - 64.0f;
    const float cy = 0.5f * (bb.y + bb.w) - 64.0f;
    const float bw = bb.z - bb.x;
    const float bh = bb.w - bb.y;

    // Each wave builds one Gaussian table (and reduces its square-sum for C):
    // wave 0: g0x (stride 4), 1: g0y (stride 4), 2: g1x (stride 8), 3: g1y (stride 8)
    {
        const float invs  = (wid < 2) ? 0.25f : 0.125f;
        const bool  horiz = !(wid & 1);
        const int   len   = (wid < 2) ? 63 : 31;
        const int   tsz   = (wid < 2) ? 64 : 32;
        float* tbl = (wid == 0) ? g0x : (wid == 1) ? g0y : (wid == 2) ? g1x : g1y;
        const float mu  = (horiz ? cx : cy) * invs;
        const float is  = 1.0f / (0.2f * (horiz ? bw : bh) * invs);
        const float amp = 0.39894228040143267794f * is;
        float v = 0.0f;
        if (lane < len) {
            float d = ((float)lane - mu) * is;
            v = amp * __expf(-0.5f * d * d);
        }
        if (lane < tsz) tbl[lane] = v;   // zero-filled beyond len
        float v2 = v * v;
        #pragma unroll
        for (int off = 32; off > 0; off >>= 1) v2 += __shfl_down(v2, off);
        if (lane == 0) sg[wid] = v2;
    }
    __syncthreads();

    // ---- level 0: 63x63, lanes = columns, wave id = row phase ----
    float T0 = 0.0f, A0 = 0.0f, B0 = 0.0f;
    if (lane < 63) {
        const float gxv = g0x[lane];
        const float* __restrict__ cb = cls0 + (size_t)sid * 3969;
        float Bc = 0.0f;
        #pragma unroll 8
        for (int y = wid; y < 63; y += 4) {
            float c   = cb[y * 63 + lane];   // coalesced 252B per wave
            float gyv = g0y[y];              // wave-uniform LDS broadcast
            T0 += c;
            A0 = fmaf(c, c, A0);
            Bc = fmaf(c, gyv, Bc);
        }
        B0 = Bc * gxv;
    }

    // ---- level 1: 31x31, 32 lanes = columns, tid/32 = row phase ----
    float T1 = 0.0f, A1 = 0.0f, B1 = 0.0f;
    {
        const int x1  = tid & 31;
        const int ty1 = tid >> 5;
        if (x1 < 31) {
            const float gxv = g1x[x1];
            const float* __restrict__ cb = cls1 + (size_t)sid * 961;
            float Bc = 0.0f;
            #pragma unroll 4
            for (int y = ty1; y < 31; y += 8) {
                float c = cb[y * 31 + x1];
                T1 += c;
                A1 = fmaf(c, c, A1);
                Bc = fmaf(c, g1y[y], Bc);
            }
            B1 = Bc * gxv;
        }
    }

    // ---- block reduction of all six partials ----
    #pragma unroll
    for (int off = 32; off > 0; off >>= 1) {
        T0 += __shfl_down(T0, off); A0 += __shfl_down(A0, off); B0 += __shfl_down(B0, off);
        T1 += __shfl_down(T1, off); A1 += __shfl_down(A1, off); B1 += __shfl_down(B1, off);
    }
    if (lane == 0) {
        red[wid][0] = T0; red[wid][1] = A0; red[wid][2] = B0;
        red[wid][3] = T1; red[wid][4] = A1; red[wid][5] = B1;
    }
    __syncthreads();
    if (tid == 0) {
        float t0 = 0, a0 = 0, b0 = 0, t1 = 0, a1 = 0, b1 = 0;
        #pragma unroll
        for (int w = 0; w < 4; ++w) {
            t0 += red[w][0]; a0 += red[w][1]; b0 += red[w][2];
            t1 += red[w][3]; a1 += red[w][4]; b1 += red[w][5];
        }
        const float C0 = sg[0] * sg[1];
        const float C1 = sg[2] * sg[3];
        const float i0 = 1.0f / t0;
        const float i1 = 1.0f / t1;
        const float l0 = (fmaf(a0 * i0, i0, -2.0f * b0 * i0) + C0) * (1.0f / 3969.0f);
        const float l1 = (fmaf(a1 * i1, i1, -2.0f * b1 * i1) + C1) * (1.0f / 961.0f);
        partial[sid] = l0 + l1;
    }
}

// Deterministic fixed-order final reduction of NSAMP partials (float4 loads).
__global__ __launch_bounds__(1024) void heat_final_kernel(
    const float* __restrict__ partial, float* __restrict__ out)
{
    __shared__ float red[16];
    const int tid = threadIdx.x;
    const float4 v = reinterpret_cast<const float4*>(partial)[tid];  // 1024*4 = 4096
    float s = (v.x + v.y) + (v.z + v.w);
    #pragma unroll
    for (int off = 32; off > 0; off >>= 1) s += __shfl_down(s, off);
    if ((tid & 63) == 0) red[tid >> 6] = s;
    __syncthreads();
    if (tid == 0) {
        float t = 0.0f;
        #pragma unroll
        for (int w = 0; w < 16; ++w) t += red[w];
        out[0] = t;
    }
}

extern "C" void kernel_launch(void* const* d_in, const int* in_sizes, int n_in,
                              void* d_out, int out_size, void* d_ws, size_t ws_size,
                              hipStream_t stream) {
    // inputs: 0=cls0 (N,1,63,63), 1=reg0 (unused), 2=cls1 (N,1,31,31),
    //         3=reg1 (unused), 4=gt_bbox (N,4)
    const float* cls0 = (const float*)d_in[0];
    const float* cls1 = (const float*)d_in[2];
    const float* gt   = (const float*)d_in[4];
    float* out = (float*)d_out;
    float* ws  = (float*)d_ws;   // NSAMP floats = 16 KiB

    heat_fused_kernel<<<NSAMP, 256, 0, stream>>>(cls0, cls1, gt, ws);
    heat_final_kernel<<<1, 1024, 0, stream>>>(ws, out);
}